// Round 9
// baseline (893.210 us; speedup 1.0000x reference)
//
#include <hip/hip_runtime.h>

#define LN_EPS 1e-5f

// Problem constants: N=2048, DIM_IN=256, DIM_V=256, VH=VW=7 (NK=49), H=64
//
// Pipeline:
//   k0_split : x -> xs_hi/xs_lo bf16 planes (trunc split)
//   gemm_sb3 : q[2048][32768] = x @ Wq^T + b   (split-bf16 3-term MFMA)
//   k2       : per-sample dynamic conv (fp32, 1024 thr) -> flat hi/lo bf16 planes
//   gemm_sb3 : wpart[14][2048][256] = flat @ Wv^T partials (split-K=14)
//   k4       : reduce 14 partials + bias -> lnv+relu -> +x -> lnf -> out
//
// ws layout (byte offsets), total 371,195,904:
//   [0, 268435456)          q fp32 [2048][32768]; reused as wpart after K2
//   [268435456, 371195904)  flat planes: hi ushort[2048][12544] @ +0,
//                                        lo @ +51380224
//   xs planes (2 MB) overlay the flat region during K0/K1 (dead by K2).

typedef __attribute__((ext_vector_type(8))) short short8;
typedef __attribute__((ext_vector_type(16))) float f32x16;

// ---------------------------------------------------------------------------
// K0: fp32 -> bf16 hi/lo planes (truncation split: exact a = hi + lo + O(2^-16))
// ---------------------------------------------------------------------------
__global__ __launch_bounds__(256) void k0_split(
    const float* __restrict__ in, ushort* __restrict__ hi,
    ushort* __restrict__ lo, int n4)
{
    const int i = blockIdx.x * 256 + threadIdx.x;
    if (i >= n4) return;
    const float4 f = ((const float4*)in)[i];
    const uint ux = __float_as_uint(f.x), uy = __float_as_uint(f.y);
    const uint uz = __float_as_uint(f.z), uw = __float_as_uint(f.w);
    ushort4 h, l;
    h.x = (ushort)(ux >> 16); h.y = (ushort)(uy >> 16);
    h.z = (ushort)(uz >> 16); h.w = (ushort)(uw >> 16);
    l.x = (ushort)(__float_as_uint(f.x - __uint_as_float(ux & 0xffff0000u)) >> 16);
    l.y = (ushort)(__float_as_uint(f.y - __uint_as_float(uy & 0xffff0000u)) >> 16);
    l.z = (ushort)(__float_as_uint(f.z - __uint_as_float(uz & 0xffff0000u)) >> 16);
    l.w = (ushort)(__float_as_uint(f.w - __uint_as_float(uw & 0xffff0000u)) >> 16);
    ((ushort4*)hi)[i] = h;
    ((ushort4*)lo)[i] = l;
}

// ---------------------------------------------------------------------------
// Split-bf16 3-term MFMA GEMM (unchanged — verified passing in rounds 6/8)
// ---------------------------------------------------------------------------
template<bool HAS_BIAS>
__global__ __launch_bounds__(256, 2) void gemm_sb3(
    const ushort* __restrict__ Ah, const ushort* __restrict__ Al,
    const float* __restrict__ B, const float* __restrict__ bias,
    float* __restrict__ C, int lda, int ldb, int ldc,
    size_t cSplitStride, int kPerSplit)
{
    __shared__ __align__(16) ushort sAh[8192];
    __shared__ __align__(16) ushort sAl[8192];
    __shared__ __align__(16) ushort sBh[8192];
    __shared__ __align__(16) ushort sBl[8192];

    const int tid = threadIdx.x;
    const int m0 = blockIdx.x << 7;
    const int j0 = blockIdx.y << 7;
    const int ks0 = blockIdx.z * kPerSplit;
    float* Cb = C + (size_t)blockIdx.z * cSplitStride;

    const int lane = tid & 63;
    const int wid = tid >> 6;
    const int wr = wid >> 1;
    const int wc = wid & 1;
    const int swz = (lane & 7) << 3;
    const int rA = (wr << 6) + (lane & 31);
    const int rB = (wc << 6) + (lane & 31);
    const int khalf = (lane >> 5) << 3;

    f32x16 acc[2][2];
#pragma unroll
    for (int r = 0; r < 2; ++r)
#pragma unroll
        for (int c = 0; c < 2; ++c)
#pragma unroll
            for (int e = 0; e < 16; ++e) acc[r][c][e] = 0.f;

    for (int kg0 = 0; kg0 < kPerSplit; kg0 += 64) {
        const int kg = ks0 + kg0;

        uint4 av[8];
#pragma unroll
        for (int p = 0; p < 2; ++p) {
            const ushort* src = p ? Al : Ah;
#pragma unroll
            for (int i = 0; i < 4; ++i) {
                const int id = tid + (i << 8);
                const int row = id >> 3;
                const int c8 = (id & 7) << 3;
                av[p * 4 + i] = *(const uint4*)(src + (size_t)(m0 + row) * lda + kg + c8);
            }
        }
        float4 bv[8];
#pragma unroll
        for (int i = 0; i < 8; ++i) {
            const int id = tid + (i << 8);
            const int row = id >> 4;
            const int c4 = (id & 15) << 2;
            bv[i] = *(const float4*)(B + (size_t)(j0 + row) * ldb + kg + c4);
        }

        if (kg0 > 0) __syncthreads();

#pragma unroll
        for (int p = 0; p < 2; ++p) {
            ushort* dst = p ? sAl : sAh;
#pragma unroll
            for (int i = 0; i < 4; ++i) {
                const int id = tid + (i << 8);
                const int row = id >> 3;
                const int c8 = (id & 7) << 3;
                *(uint4*)&dst[((row << 6) + c8) ^ ((row & 7) << 3)] = av[p * 4 + i];
            }
        }
#pragma unroll
        for (int i = 0; i < 8; ++i) {
            const int id = tid + (i << 8);
            const int row = id >> 4;
            const int c4 = (id & 15) << 2;
            const uint ux = __float_as_uint(bv[i].x), uy = __float_as_uint(bv[i].y);
            const uint uz = __float_as_uint(bv[i].z), uw = __float_as_uint(bv[i].w);
            const float lx = bv[i].x - __uint_as_float(ux & 0xffff0000u);
            const float ly = bv[i].y - __uint_as_float(uy & 0xffff0000u);
            const float lz = bv[i].z - __uint_as_float(uz & 0xffff0000u);
            const float lw = bv[i].w - __uint_as_float(uw & 0xffff0000u);
            const uint h01 = (ux >> 16) | (uy & 0xffff0000u);
            const uint h23 = (uz >> 16) | (uw & 0xffff0000u);
            const uint l01 = (__float_as_uint(lx) >> 16) | (__float_as_uint(ly) & 0xffff0000u);
            const uint l23 = (__float_as_uint(lz) >> 16) | (__float_as_uint(lw) & 0xffff0000u);
            const int sidx = ((row << 6) + c4) ^ ((row & 7) << 3);
            *(uint2*)&sBh[sidx] = make_uint2(h01, h23);
            *(uint2*)&sBl[sidx] = make_uint2(l01, l23);
        }
        __syncthreads();

#pragma unroll
        for (int ks = 0; ks < 4; ++ks) {
            const int kf = (ks << 4) + khalf;
            const int ia0 = ((rA << 6) + kf) ^ swz;
            const int ia1 = (((rA + 32) << 6) + kf) ^ swz;
            const int ib0 = ((rB << 6) + kf) ^ swz;
            const int ib1 = (((rB + 32) << 6) + kf) ^ swz;
            const short8 a0h = *(const short8*)&sAh[ia0];
            const short8 a0l = *(const short8*)&sAl[ia0];
            const short8 a1h = *(const short8*)&sAh[ia1];
            const short8 a1l = *(const short8*)&sAl[ia1];
            const short8 b0h = *(const short8*)&sBh[ib0];
            const short8 b0l = *(const short8*)&sBl[ib0];
            const short8 b1h = *(const short8*)&sBh[ib1];
            const short8 b1l = *(const short8*)&sBl[ib1];

            acc[0][0] = __builtin_amdgcn_mfma_f32_32x32x16_bf16(a0h, b0h, acc[0][0], 0, 0, 0);
            acc[0][1] = __builtin_amdgcn_mfma_f32_32x32x16_bf16(a0h, b1h, acc[0][1], 0, 0, 0);
            acc[1][0] = __builtin_amdgcn_mfma_f32_32x32x16_bf16(a1h, b0h, acc[1][0], 0, 0, 0);
            acc[1][1] = __builtin_amdgcn_mfma_f32_32x32x16_bf16(a1h, b1h, acc[1][1], 0, 0, 0);
            acc[0][0] = __builtin_amdgcn_mfma_f32_32x32x16_bf16(a0h, b0l, acc[0][0], 0, 0, 0);
            acc[0][1] = __builtin_amdgcn_mfma_f32_32x32x16_bf16(a0h, b1l, acc[0][1], 0, 0, 0);
            acc[1][0] = __builtin_amdgcn_mfma_f32_32x32x16_bf16(a1h, b0l, acc[1][0], 0, 0, 0);
            acc[1][1] = __builtin_amdgcn_mfma_f32_32x32x16_bf16(a1h, b1l, acc[1][1], 0, 0, 0);
            acc[0][0] = __builtin_amdgcn_mfma_f32_32x32x16_bf16(a0l, b0h, acc[0][0], 0, 0, 0);
            acc[0][1] = __builtin_amdgcn_mfma_f32_32x32x16_bf16(a0l, b1h, acc[0][1], 0, 0, 0);
            acc[1][0] = __builtin_amdgcn_mfma_f32_32x32x16_bf16(a1l, b0h, acc[1][0], 0, 0, 0);
            acc[1][1] = __builtin_amdgcn_mfma_f32_32x32x16_bf16(a1l, b1h, acc[1][1], 0, 0, 0);
        }
    }

#pragma unroll
    for (int rb = 0; rb < 2; ++rb)
#pragma unroll
        for (int cb = 0; cb < 2; ++cb) {
            const int col = j0 + (wc << 6) + (cb << 5) + (lane & 31);
            const float bvv = HAS_BIAS ? bias[col] : 0.0f;
            const int rbase = m0 + (wr << 6) + (rb << 5) + ((lane >> 5) << 2);
            float* cp = Cb + (size_t)rbase * ldc + col;
#pragma unroll
            for (int reg = 0; reg < 16; ++reg) {
                const int rr = (reg & 3) + ((reg >> 2) << 3);
                cp[(size_t)rr * ldc] = acc[rb][cb][reg] + bvv;
            }
        }
}

// ---------------------------------------------------------------------------
// K2: per-sample dynamic conv, 1024 threads (16 waves), 1 wg/sample.
// Round-9 changes (spill fix — round 8: VGPR_Count=64, WRITE_SIZE 247 MB ≈
// 196 MB scratch):
//   - __launch_bounds__(1024, 4): 4 waves/EU = our exact residency -> 128 VGPR cap
//   - phase B re-tiled 8k x 8j (224 thr, ~104 live regs) -> 4k x 8j (416 thr,
//     ~70 live regs): no spill, 2x phase-B parallelism
// LDS: vL [256][52] (13312) | pL 16384 (p1 then p2) | tL [52][68] (3332)
// ---------------------------------------------------------------------------
__global__ __launch_bounds__(1024, 4) void k2_dynconv(
    const float* __restrict__ v, const float* __restrict__ q,
    const float* __restrict__ ln0g, const float* __restrict__ ln0b,
    const float* __restrict__ ln1g, const float* __restrict__ ln1b,
    ushort* __restrict__ fhi, ushort* __restrict__ flo)
{
    __shared__ __align__(16) float sm[33028];    // 132,112 B
    float* const vL = sm;                        // 13312
    float* const pL = sm + 13312;                // 16384
    float* const tL = sm + 29696;                // 3332

    const int n = blockIdx.x;
    const int tid = threadIdx.x;
    const float* vrow = v + (size_t)n * 12544;
    const float* qrow = q + (size_t)n * 32768;

    // ---- p2 prefetch into registers (latency hides under staging + phase A)
    float4 rp2[4];
#pragma unroll
    for (int j = 0; j < 4; ++j)
        rp2[j] = *(const float4*)(qrow + 16384 + ((tid + j * 1024) << 2));

    // ---- stage p1 (f4 linear)
#pragma unroll
    for (int j = 0; j < 4; ++j) {
        const int c = tid + j * 1024;
        *(float4*)&pL[c << 2] = *(const float4*)(qrow + (c << 2));
    }
    // ---- stage v: coalesced f4 load, re-stride 49->52 with magic-div by 49
#pragma unroll
    for (int j = 0; j < 4; ++j) {
        const int c = tid + j * 1024;
        if (c < 3136) {
            const float4 f = *(const float4*)(vrow + (c << 2));
            const int i0 = c << 2;
#pragma unroll
            for (int e = 0; e < 4; ++e) {
                const int i = i0 + e;
                const int dv = (int)(((uint)i * 85599u) >> 22);   // i/49, exact for i<89k
                const int k = i - dv * 49;
                vL[dv * 52 + k] = ((const float*)&f)[e];
            }
        }
    }
    __syncthreads();

    // ---- phase A: t1[49][64] = vt @ p1 ; 208 threads, 4k x 4h
    float ta[4][4];
    const int ktA = tid >> 4;              // k-tile (rows 4*ktA..+3)
    const int h0A = (tid & 15) << 2;
    if (tid < 208) {
#pragma unroll
        for (int r = 0; r < 4; ++r)
#pragma unroll
            for (int c = 0; c < 4; ++c) ta[r][c] = 0.f;
        int aoff[4];
#pragma unroll
        for (int r = 0; r < 4; ++r) {
            const int k = (ktA << 2) + r;
            aoff[r] = (k < 49 ? k : 48) * 52;
        }
#pragma unroll 2
        for (int dv = 0; dv < 256; dv += 1) {
            const float4 b4 = *(const float4*)&pL[(dv << 6) + h0A];
            const float* bp = (const float*)&b4;
            float a[4];
#pragma unroll
            for (int r = 0; r < 4; ++r) a[r] = vL[dv * 52 + ((ktA << 2) + r < 49 ? (ktA << 2) + r : 48)];
#pragma unroll
            for (int r = 0; r < 4; ++r)
#pragma unroll
                for (int c = 0; c < 4; ++c)
                    ta[r][c] = fmaf(a[r], bp[c], ta[r][c]);
        }
        (void)aoff;
    }
    __syncthreads();   // phase A done reading vL/pL

    // ---- p2 regs -> LDS (all 1024 threads)
#pragma unroll
    for (int j = 0; j < 4; ++j)
        *(float4*)&pL[(tid + j * 1024) << 2] = rp2[j];

    // ---- LN0 + relu in-register (row k spread over 16 contiguous lanes)
    if (tid < 208) {
        float s1[4], s2[4];
#pragma unroll
        for (int r = 0; r < 4; ++r) {
            s1[r] = ta[r][0] + ta[r][1] + ta[r][2] + ta[r][3];
            s2[r] = ta[r][0]*ta[r][0] + ta[r][1]*ta[r][1]
                  + ta[r][2]*ta[r][2] + ta[r][3]*ta[r][3];
        }
#pragma unroll
        for (int m = 1; m < 16; m <<= 1)
#pragma unroll
            for (int r = 0; r < 4; ++r) {
                s1[r] += __shfl_xor(s1[r], m);
                s2[r] += __shfl_xor(s2[r], m);
            }
        const float4 g4 = *(const float4*)&ln0g[h0A];
        const float4 b4 = *(const float4*)&ln0b[h0A];
        const float* gp = (const float*)&g4;
        const float* bp = (const float*)&b4;
#pragma unroll
        for (int r = 0; r < 4; ++r) {
            const int k = (ktA << 2) + r;
            if (k < 49) {
                const float mean = s1[r] * (1.f / 64.f);
                const float var = s2[r] * (1.f / 64.f) - mean * mean;
                const float rstd = rsqrtf(var + LN_EPS);
                float4 o;
                o.x = fmaxf((ta[r][0] - mean) * rstd * gp[0] + bp[0], 0.f);
                o.y = fmaxf((ta[r][1] - mean) * rstd * gp[1] + bp[1], 0.f);
                o.z = fmaxf((ta[r][2] - mean) * rstd * gp[2] + bp[2], 0.f);
                o.w = fmaxf((ta[r][3] - mean) * rstd * gp[3] + bp[3], 0.f);
                *(float4*)&tL[k * 68 + h0A] = o;
            }
        }
    }
    __syncthreads();   // p2 staged + th ready

    // ---- phase B: t2[49][256] = th @ p2 ; 416 threads, 4k x 8j (~70 live regs)
    if (tid < 416) {
        const int ktB = tid >> 5;              // 0..12 (rows 4*ktB..+3, clamped)
        const int j0B = (tid & 31) << 3;
        int roff[4];
#pragma unroll
        for (int r = 0; r < 4; ++r) {
            const int k = (ktB << 2) + r;
            roff[r] = (k < 49 ? k : 48) * 68;
        }
        float acc[4][8];
#pragma unroll
        for (int r = 0; r < 4; ++r)
#pragma unroll
            for (int c = 0; c < 8; ++c) acc[r][c] = 0.f;

        for (int hb = 0; hb < 16; ++hb) {      // 4 h per block
            float4 a4[4];
#pragma unroll
            for (int r = 0; r < 4; ++r)
                a4[r] = *(const float4*)&tL[roff[r] + (hb << 2)];
#pragma unroll
            for (int hh = 0; hh < 4; ++hh) {
                const int h = (hb << 2) + hh;
                const float4 b0 = *(const float4*)&pL[(h << 8) + j0B];
                const float4 b1 = *(const float4*)&pL[(h << 8) + j0B + 4];
                const float* bp0 = (const float*)&b0;
                const float* bp1 = (const float*)&b1;
#pragma unroll
                for (int r = 0; r < 4; ++r) {
                    const float a = ((const float*)&a4[r])[hh];
#pragma unroll
                    for (int c = 0; c < 4; ++c) {
                        acc[r][c]     = fmaf(a, bp0[c], acc[r][c]);
                        acc[r][c + 4] = fmaf(a, bp1[c], acc[r][c + 4]);
                    }
                }
            }
        }

        // ---- LN1 + relu in-register (row spread over 32 contiguous lanes)
        float s1[4], s2[4];
#pragma unroll
        for (int r = 0; r < 4; ++r) {
            float a1 = 0.f, a2 = 0.f;
#pragma unroll
            for (int c = 0; c < 8; ++c) { a1 += acc[r][c]; a2 += acc[r][c] * acc[r][c]; }
            s1[r] = a1; s2[r] = a2;
        }
#pragma unroll
        for (int m = 1; m < 32; m <<= 1)
#pragma unroll
            for (int r = 0; r < 4; ++r) {
                s1[r] += __shfl_xor(s1[r], m);
                s2[r] += __shfl_xor(s2[r], m);
            }
        const float4 g0 = *(const float4*)&ln1g[j0B];
        const float4 g1 = *(const float4*)&ln1g[j0B + 4];
        const float4 bb0 = *(const float4*)&ln1b[j0B];
        const float4 bb1 = *(const float4*)&ln1b[j0B + 4];
        const float* gp = (const float*)&g0;
        const float* gq = (const float*)&g1;
        const float* bp = (const float*)&bb0;
        const float* bq = (const float*)&bb1;
#pragma unroll
        for (int r = 0; r < 4; ++r) {
            const int k = (ktB << 2) + r;
            if (k < 49) {
                const float mean = s1[r] * (1.f / 256.f);
                const float var = s2[r] * (1.f / 256.f) - mean * mean;
                const float rstd = rsqrtf(var + LN_EPS);
                float o[8];
#pragma unroll
                for (int c = 0; c < 4; ++c) {
                    o[c]     = fmaxf((acc[r][c]     - mean) * rstd * gp[c] + bp[c], 0.f);
                    o[c + 4] = fmaxf((acc[r][c + 4] - mean) * rstd * gq[c] + bq[c], 0.f);
                }
                ushort4 h4a, h4b, l4a, l4b;
#pragma unroll
                for (int c = 0; c < 4; ++c) {
                    const uint u = __float_as_uint(o[c]);
                    ((ushort*)&h4a)[c] = (ushort)(u >> 16);
                    ((ushort*)&l4a)[c] = (ushort)(__float_as_uint(o[c] - __uint_as_float(u & 0xffff0000u)) >> 16);
                    const uint u2 = __float_as_uint(o[c + 4]);
                    ((ushort*)&h4b)[c] = (ushort)(u2 >> 16);
                    ((ushort*)&l4b)[c] = (ushort)(__float_as_uint(o[c + 4] - __uint_as_float(u2 & 0xffff0000u)) >> 16);
                }
                const size_t fo = (size_t)n * 12544 + k * 256 + j0B;
                *(ushort4*)&fhi[fo] = h4a;
                *(ushort4*)&fhi[fo + 4] = h4b;
                *(ushort4*)&flo[fo] = l4a;
                *(ushort4*)&flo[fo + 4] = l4b;
            }
        }
    }
}

// ---------------------------------------------------------------------------
// K4: reduce 14 split-K partials + Wv_b -> lnv+relu -> +x -> lnf -> out.
// ---------------------------------------------------------------------------
__global__ __launch_bounds__(256) void k4_final(
    const float* __restrict__ wpart, const float* __restrict__ x,
    const float* __restrict__ Wvb,
    const float* __restrict__ lnvg, const float* __restrict__ lnvb,
    const float* __restrict__ lnfg, const float* __restrict__ lnfb,
    float* __restrict__ out)
{
    const int n = (blockIdx.x << 2) + (threadIdx.x >> 6);
    const int lane = threadIdx.x & 63;
    const int j = lane << 2;

    float a0 = 0.f, a1 = 0.f, a2 = 0.f, a3 = 0.f;
#pragma unroll
    for (int s = 0; s < 14; ++s) {
        const float4 p = *(const float4*)&wpart[((size_t)s * 2048 + n) * 256 + j];
        a0 += p.x; a1 += p.y; a2 += p.z; a3 += p.w;
    }
    const float4 bb = *(const float4*)&Wvb[j];
    a0 += bb.x; a1 += bb.y; a2 += bb.z; a3 += bb.w;

    float s1 = a0 + a1 + a2 + a3;
    float s2 = a0*a0 + a1*a1 + a2*a2 + a3*a3;
#pragma unroll
    for (int off = 32; off > 0; off >>= 1) {
        s1 += __shfl_xor(s1, off);
        s2 += __shfl_xor(s2, off);
    }
    float m = s1 * (1.f / 256.f);
    float var = s2 * (1.f / 256.f) - m * m;
    float rr = rsqrtf(var + LN_EPS);
    const float4 g = *(const float4*)&lnvg[j];
    const float4 b = *(const float4*)&lnvb[j];
    const float w0 = fmaxf((a0 - m) * rr * g.x + b.x, 0.f);
    const float w1 = fmaxf((a1 - m) * rr * g.y + b.y, 0.f);
    const float w2 = fmaxf((a2 - m) * rr * g.z + b.z, 0.f);
    const float w3 = fmaxf((a3 - m) * rr * g.w + b.w, 0.f);

    const float4 xv = *(const float4*)&x[(size_t)n * 256 + j];
    const float t0 = xv.x + w0, t1 = xv.y + w1, t2 = xv.z + w2, t3 = xv.w + w3;
    s1 = t0 + t1 + t2 + t3;
    s2 = t0*t0 + t1*t1 + t2*t2 + t3*t3;
#pragma unroll
    for (int off = 32; off > 0; off >>= 1) {
        s1 += __shfl_xor(s1, off);
        s2 += __shfl_xor(s2, off);
    }
    m = s1 * (1.f / 256.f);
    var = s2 * (1.f / 256.f) - m * m;
    rr = rsqrtf(var + LN_EPS);
    const float4 gf = *(const float4*)&lnfg[j];
    const float4 bf = *(const float4*)&lnfb[j];
    float4 o;
    o.x = (t0 - m) * rr * gf.x + bf.x;
    o.y = (t1 - m) * rr * gf.y + bf.y;
    o.z = (t2 - m) * rr * gf.z + bf.z;
    o.w = (t3 - m) * rr * gf.w + bf.w;
    *(float4*)&out[(size_t)n * 256 + j] = o;
}

// ---------------------------------------------------------------------------
extern "C" void kernel_launch(void* const* d_in, const int* in_sizes, int n_in,
                              void* d_out, int out_size, void* d_ws, size_t ws_size,
                              hipStream_t stream)
{
    const float* x    = (const float*)d_in[0];
    const float* v    = (const float*)d_in[1];
    const float* Wq_w = (const float*)d_in[2];
    const float* Wq_b = (const float*)d_in[3];
    const float* ln0g = (const float*)d_in[4];
    const float* ln0b = (const float*)d_in[5];
    const float* ln1g = (const float*)d_in[6];
    const float* ln1b = (const float*)d_in[7];
    const float* Wv_w = (const float*)d_in[8];
    const float* Wv_b = (const float*)d_in[9];
    const float* lnvg = (const float*)d_in[10];
    const float* lnvb = (const float*)d_in[11];
    const float* lnfg = (const float*)d_in[12];
    const float* lnfb = (const float*)d_in[13];
    float* out = (float*)d_out;

    if (ws_size < 371195904ull) return;  // loud failure: out stays poisoned
    char* ws = (char*)d_ws;
    float* q        = (float*)ws;                          // [2048][32768] fp32
    ushort* flat_hi = (ushort*)(ws + 268435456u);          // [2048][12544] bf16
    ushort* flat_lo = (ushort*)(ws + 319815680u);
    ushort* xs_hi   = (ushort*)(ws + 268435456u);          // overlay (dead by K2)
    ushort* xs_lo   = xs_hi + 524288;
    float* wpart    = q;                                   // [14][2048][256] fp32

    k0_split<<<512, 256, 0, stream>>>(x, xs_hi, xs_lo, 131072);

    gemm_sb3<true><<<dim3(16, 256, 1), 256, 0, stream>>>(
        xs_hi, xs_lo, Wq_w, Wq_b, q, 256, 256, 32768, 0, 256);

    k2_dynconv<<<2048, 1024, 0, stream>>>(v, q, ln0g, ln0b, ln1g, ln1b,
                                          flat_hi, flat_lo);

    gemm_sb3<false><<<dim3(16, 2, 14), 256, 0, stream>>>(
        flat_hi, flat_lo, Wv_w, nullptr, wpart, 12544, 12544, 256,
        (size_t)2048 * 256, 896);

    k4_final<<<512, 256, 0, stream>>>(wpart, x, Wv_b, lnvg, lnvb, lnfg, lnfb, out);
}

// Round 10
// 803.442 us; speedup vs baseline: 1.1117x; 1.1117x over previous
//
#include <hip/hip_runtime.h>

#define LN_EPS 1e-5f

// Problem constants: N=2048, DIM_IN=256, DIM_V=256, VH=VW=7 (NK=49), H=64
//
// Pipeline:
//   k0_split : x -> xs_hi/xs_lo bf16 planes (trunc split)
//   gemm_sb3 : q[2048][32768] = x @ Wq^T + b   (split-bf16 3-term MFMA)
//   k2       : per-sample dynamic conv (fp32, 512 thr, chunked LDS)
//   gemm_sb3 : wpart[14][2048][256] = flat @ Wv^T partials (split-K=14)
//   k4       : reduce 14 partials + bias -> lnv+relu -> +x -> lnf -> out
//
// ws layout (byte offsets), total 371,195,904:
//   [0, 268435456)          q fp32 [2048][32768]; reused as wpart after K2
//   [268435456, 371195904)  flat planes: hi ushort[2048][12544] @ +0,
//                                        lo @ +51380224
//   xs planes (2 MB) overlay the flat region during K0/K1 (dead by K2).

typedef __attribute__((ext_vector_type(8))) short short8;
typedef __attribute__((ext_vector_type(16))) float f32x16;

// ---------------------------------------------------------------------------
// K0: fp32 -> bf16 hi/lo planes (truncation split: exact a = hi + lo + O(2^-16))
// ---------------------------------------------------------------------------
__global__ __launch_bounds__(256) void k0_split(
    const float* __restrict__ in, ushort* __restrict__ hi,
    ushort* __restrict__ lo, int n4)
{
    const int i = blockIdx.x * 256 + threadIdx.x;
    if (i >= n4) return;
    const float4 f = ((const float4*)in)[i];
    const uint ux = __float_as_uint(f.x), uy = __float_as_uint(f.y);
    const uint uz = __float_as_uint(f.z), uw = __float_as_uint(f.w);
    ushort4 h, l;
    h.x = (ushort)(ux >> 16); h.y = (ushort)(uy >> 16);
    h.z = (ushort)(uz >> 16); h.w = (ushort)(uw >> 16);
    l.x = (ushort)(__float_as_uint(f.x - __uint_as_float(ux & 0xffff0000u)) >> 16);
    l.y = (ushort)(__float_as_uint(f.y - __uint_as_float(uy & 0xffff0000u)) >> 16);
    l.z = (ushort)(__float_as_uint(f.z - __uint_as_float(uz & 0xffff0000u)) >> 16);
    l.w = (ushort)(__float_as_uint(f.w - __uint_as_float(uw & 0xffff0000u)) >> 16);
    ((ushort4*)hi)[i] = h;
    ((ushort4*)lo)[i] = l;
}

// ---------------------------------------------------------------------------
// Split-bf16 3-term MFMA GEMM (unchanged — verified passing rounds 6/8/9)
// ---------------------------------------------------------------------------
template<bool HAS_BIAS>
__global__ __launch_bounds__(256, 2) void gemm_sb3(
    const ushort* __restrict__ Ah, const ushort* __restrict__ Al,
    const float* __restrict__ B, const float* __restrict__ bias,
    float* __restrict__ C, int lda, int ldb, int ldc,
    size_t cSplitStride, int kPerSplit)
{
    __shared__ __align__(16) ushort sAh[8192];
    __shared__ __align__(16) ushort sAl[8192];
    __shared__ __align__(16) ushort sBh[8192];
    __shared__ __align__(16) ushort sBl[8192];

    const int tid = threadIdx.x;
    const int m0 = blockIdx.x << 7;
    const int j0 = blockIdx.y << 7;
    const int ks0 = blockIdx.z * kPerSplit;
    float* Cb = C + (size_t)blockIdx.z * cSplitStride;

    const int lane = tid & 63;
    const int wid = tid >> 6;
    const int wr = wid >> 1;
    const int wc = wid & 1;
    const int swz = (lane & 7) << 3;
    const int rA = (wr << 6) + (lane & 31);
    const int rB = (wc << 6) + (lane & 31);
    const int khalf = (lane >> 5) << 3;

    f32x16 acc[2][2];
#pragma unroll
    for (int r = 0; r < 2; ++r)
#pragma unroll
        for (int c = 0; c < 2; ++c)
#pragma unroll
            for (int e = 0; e < 16; ++e) acc[r][c][e] = 0.f;

    for (int kg0 = 0; kg0 < kPerSplit; kg0 += 64) {
        const int kg = ks0 + kg0;

        uint4 av[8];
#pragma unroll
        for (int p = 0; p < 2; ++p) {
            const ushort* src = p ? Al : Ah;
#pragma unroll
            for (int i = 0; i < 4; ++i) {
                const int id = tid + (i << 8);
                const int row = id >> 3;
                const int c8 = (id & 7) << 3;
                av[p * 4 + i] = *(const uint4*)(src + (size_t)(m0 + row) * lda + kg + c8);
            }
        }
        float4 bv[8];
#pragma unroll
        for (int i = 0; i < 8; ++i) {
            const int id = tid + (i << 8);
            const int row = id >> 4;
            const int c4 = (id & 15) << 2;
            bv[i] = *(const float4*)(B + (size_t)(j0 + row) * ldb + kg + c4);
        }

        if (kg0 > 0) __syncthreads();

#pragma unroll
        for (int p = 0; p < 2; ++p) {
            ushort* dst = p ? sAl : sAh;
#pragma unroll
            for (int i = 0; i < 4; ++i) {
                const int id = tid + (i << 8);
                const int row = id >> 3;
                const int c8 = (id & 7) << 3;
                *(uint4*)&dst[((row << 6) + c8) ^ ((row & 7) << 3)] = av[p * 4 + i];
            }
        }
#pragma unroll
        for (int i = 0; i < 8; ++i) {
            const int id = tid + (i << 8);
            const int row = id >> 4;
            const int c4 = (id & 15) << 2;
            const uint ux = __float_as_uint(bv[i].x), uy = __float_as_uint(bv[i].y);
            const uint uz = __float_as_uint(bv[i].z), uw = __float_as_uint(bv[i].w);
            const float lx = bv[i].x - __uint_as_float(ux & 0xffff0000u);
            const float ly = bv[i].y - __uint_as_float(uy & 0xffff0000u);
            const float lz = bv[i].z - __uint_as_float(uz & 0xffff0000u);
            const float lw = bv[i].w - __uint_as_float(uw & 0xffff0000u);
            const uint h01 = (ux >> 16) | (uy & 0xffff0000u);
            const uint h23 = (uz >> 16) | (uw & 0xffff0000u);
            const uint l01 = (__float_as_uint(lx) >> 16) | (__float_as_uint(ly) & 0xffff0000u);
            const uint l23 = (__float_as_uint(lz) >> 16) | (__float_as_uint(lw) & 0xffff0000u);
            const int sidx = ((row << 6) + c4) ^ ((row & 7) << 3);
            *(uint2*)&sBh[sidx] = make_uint2(h01, h23);
            *(uint2*)&sBl[sidx] = make_uint2(l01, l23);
        }
        __syncthreads();

#pragma unroll
        for (int ks = 0; ks < 4; ++ks) {
            const int kf = (ks << 4) + khalf;
            const int ia0 = ((rA << 6) + kf) ^ swz;
            const int ia1 = (((rA + 32) << 6) + kf) ^ swz;
            const int ib0 = ((rB << 6) + kf) ^ swz;
            const int ib1 = (((rB + 32) << 6) + kf) ^ swz;
            const short8 a0h = *(const short8*)&sAh[ia0];
            const short8 a0l = *(const short8*)&sAl[ia0];
            const short8 a1h = *(const short8*)&sAh[ia1];
            const short8 a1l = *(const short8*)&sAl[ia1];
            const short8 b0h = *(const short8*)&sBh[ib0];
            const short8 b0l = *(const short8*)&sBl[ib0];
            const short8 b1h = *(const short8*)&sBh[ib1];
            const short8 b1l = *(const short8*)&sBl[ib1];

            acc[0][0] = __builtin_amdgcn_mfma_f32_32x32x16_bf16(a0h, b0h, acc[0][0], 0, 0, 0);
            acc[0][1] = __builtin_amdgcn_mfma_f32_32x32x16_bf16(a0h, b1h, acc[0][1], 0, 0, 0);
            acc[1][0] = __builtin_amdgcn_mfma_f32_32x32x16_bf16(a1h, b0h, acc[1][0], 0, 0, 0);
            acc[1][1] = __builtin_amdgcn_mfma_f32_32x32x16_bf16(a1h, b1h, acc[1][1], 0, 0, 0);
            acc[0][0] = __builtin_amdgcn_mfma_f32_32x32x16_bf16(a0h, b0l, acc[0][0], 0, 0, 0);
            acc[0][1] = __builtin_amdgcn_mfma_f32_32x32x16_bf16(a0h, b1l, acc[0][1], 0, 0, 0);
            acc[1][0] = __builtin_amdgcn_mfma_f32_32x32x16_bf16(a1h, b0l, acc[1][0], 0, 0, 0);
            acc[1][1] = __builtin_amdgcn_mfma_f32_32x32x16_bf16(a1h, b1l, acc[1][1], 0, 0, 0);
            acc[0][0] = __builtin_amdgcn_mfma_f32_32x32x16_bf16(a0l, b0h, acc[0][0], 0, 0, 0);
            acc[0][1] = __builtin_amdgcn_mfma_f32_32x32x16_bf16(a0l, b1h, acc[0][1], 0, 0, 0);
            acc[1][0] = __builtin_amdgcn_mfma_f32_32x32x16_bf16(a1l, b0h, acc[1][0], 0, 0, 0);
            acc[1][1] = __builtin_amdgcn_mfma_f32_32x32x16_bf16(a1l, b1h, acc[1][1], 0, 0, 0);
        }
    }

#pragma unroll
    for (int rb = 0; rb < 2; ++rb)
#pragma unroll
        for (int cb = 0; cb < 2; ++cb) {
            const int col = j0 + (wc << 6) + (cb << 5) + (lane & 31);
            const float bvv = HAS_BIAS ? bias[col] : 0.0f;
            const int rbase = m0 + (wr << 6) + (rb << 5) + ((lane >> 5) << 2);
            float* cp = Cb + (size_t)rbase * ldc + col;
#pragma unroll
            for (int reg = 0; reg < 16; ++reg) {
                const int rr = (reg & 3) + ((reg >> 2) << 3);
                cp[(size_t)rr * ldc] = acc[rb][cb][reg] + bvv;
            }
        }
}

// ---------------------------------------------------------------------------
// K2 (v4): per-sample dynamic conv, 512 threads (8 waves), chunked LDS 43 KB.
//   - __launch_bounds__(512,4): 128-VGPR cap, max live ~70 -> spill-proof
//   - phase A: dv-chunks of 64 (vL [64][52] + pL [64][64] linear); 208 thr 4kx4h
//   - LN0 in-register (16-lane shfl) -> thL [49][68]
//   - phase B: h-chunks of 16 (pL as [16][256], XOR-swizzled f4 granules
//     s = g ^ (g>>3) to break the 8-way j-stride bank conflict); 416 thr 4kx8j
//   - LN1 in-register (32-lane shfl) -> flat hi/lo bf16 direct to global
// ---------------------------------------------------------------------------
__global__ __launch_bounds__(512, 4) void k2_dynconv(
    const float* __restrict__ v, const float* __restrict__ q,
    const float* __restrict__ ln0g, const float* __restrict__ ln0b,
    const float* __restrict__ ln1g, const float* __restrict__ ln1b,
    ushort* __restrict__ fhi, ushort* __restrict__ flo)
{
    __shared__ __align__(16) float sm[10756];    // 43,024 B -> 2-3 wgs/CU
    float* const thL = sm;                       // [49][68] = 3332
    float* const vL  = sm + 3332;                // [64][52] = 3328
    float* const pL  = sm + 6660;                // 4096 (A: [64][64]; B: [16][256] swz)

    const int n = blockIdx.x;
    const int tid = threadIdx.x;
    const float* vrow = v + (size_t)n * 12544;
    const float* qrow = q + (size_t)n * 32768;

    // ======== phase A: t1[49][64] = vt @ p1, chunked over dv (4 x 64) ========
    const int ktA = tid >> 4;                    // <13 for tid<208
    const int h0A = (tid & 15) << 2;
    float ta[4][4];
#pragma unroll
    for (int r = 0; r < 4; ++r)
#pragma unroll
        for (int c = 0; c < 4; ++c) ta[r][c] = 0.f;

    for (int ch = 0; ch < 4; ++ch) {
        if (ch) __syncthreads();                 // prev chunk's readers done
        // stage v chunk (dv in [64ch, 64ch+64)): 3136 floats, f4 loads + scatter
        for (int i4 = tid; i4 < 784; i4 += 512) {
            const float4 f = *(const float4*)(vrow + ch * 3136 + (i4 << 2));
            const int base = i4 << 2;
#pragma unroll
            for (int e = 0; e < 4; ++e) {
                const int idx = base + e;                       // 0..3135
                const int dv = (int)(((uint)idx * 85599u) >> 22); // /49 exact
                const int k = idx - dv * 49;
                vL[dv * 52 + k] = ((const float*)&f)[e];
            }
        }
        // stage p1 chunk [64 dv][64 h] linear: 1024 f4
        for (int i = tid; i < 1024; i += 512)
            *(float4*)&pL[i << 2] = *(const float4*)(qrow + (ch << 12) + (i << 2));
        __syncthreads();

        if (tid < 208) {
#pragma unroll 2
            for (int dv = 0; dv < 64; ++dv) {
                const float4 a4 = *(const float4*)&vL[dv * 52 + (ktA << 2)];
                const float4 b4 = *(const float4*)&pL[(dv << 6) + h0A];
                const float* ap = (const float*)&a4;
                const float* bp = (const float*)&b4;
#pragma unroll
                for (int r = 0; r < 4; ++r)
#pragma unroll
                    for (int c = 0; c < 4; ++c)
                        ta[r][c] = fmaf(ap[r], bp[c], ta[r][c]);
            }
        }
    }

    // ---- LN0 + relu in-register (row k on 16 contiguous lanes) -> thL
    if (tid < 208) {
        float s1[4], s2[4];
#pragma unroll
        for (int r = 0; r < 4; ++r) {
            s1[r] = ta[r][0] + ta[r][1] + ta[r][2] + ta[r][3];
            s2[r] = ta[r][0]*ta[r][0] + ta[r][1]*ta[r][1]
                  + ta[r][2]*ta[r][2] + ta[r][3]*ta[r][3];
        }
#pragma unroll
        for (int m = 1; m < 16; m <<= 1)
#pragma unroll
            for (int r = 0; r < 4; ++r) {
                s1[r] += __shfl_xor(s1[r], m);
                s2[r] += __shfl_xor(s2[r], m);
            }
        const float4 g4 = *(const float4*)&ln0g[h0A];
        const float4 b4 = *(const float4*)&ln0b[h0A];
        const float* gp = (const float*)&g4;
        const float* bp = (const float*)&b4;
#pragma unroll
        for (int r = 0; r < 4; ++r) {
            const int k = (ktA << 2) + r;
            if (k < 49) {
                const float mean = s1[r] * (1.f / 64.f);
                const float var = s2[r] * (1.f / 64.f) - mean * mean;
                const float rstd = rsqrtf(var + LN_EPS);
                float4 o;
                o.x = fmaxf((ta[r][0] - mean) * rstd * gp[0] + bp[0], 0.f);
                o.y = fmaxf((ta[r][1] - mean) * rstd * gp[1] + bp[1], 0.f);
                o.z = fmaxf((ta[r][2] - mean) * rstd * gp[2] + bp[2], 0.f);
                o.w = fmaxf((ta[r][3] - mean) * rstd * gp[3] + bp[3], 0.f);
                *(float4*)&thL[k * 68 + h0A] = o;
            }
        }
    }
    __syncthreads();   // A-compute done with pL; thL visible

    // ======== phase B: t2[49][256] = th @ p2, chunked over h (4 x 16) ========
    const int ktB = tid >> 5;                    // <13 for tid<416
    const int j0B = (tid & 31) << 3;
    const int g0 = (tid & 31) << 1;              // f4 granule pair g0, g0+1
    const int sw0 = (g0 ^ (g0 >> 3)) << 2;       // swizzled float offsets
    const int sw1 = ((g0 + 1) ^ ((g0 + 1) >> 3)) << 2;
    int roffB[4];
#pragma unroll
    for (int r = 0; r < 4; ++r) {
        const int k = (ktB << 2) + r;
        roffB[r] = (k < 49 ? k : 48) * 68;
    }
    float acc[4][8];
#pragma unroll
    for (int r = 0; r < 4; ++r)
#pragma unroll
        for (int c = 0; c < 8; ++c) acc[r][c] = 0.f;

    for (int ch = 0; ch < 4; ++ch) {
        if (ch) __syncthreads();                 // prev chunk's readers done
        // stage p2 chunk [16 h][256 j], XOR-swizzled f4 granules
        for (int i = tid; i < 1024; i += 512) {
            const int h = i >> 6;
            const int g = i & 63;
            const int s = g ^ (g >> 3);
            *(float4*)&pL[(h << 8) + (s << 2)] =
                *(const float4*)(qrow + 16384 + (ch << 12) + (i << 2));
        }
        __syncthreads();

        if (tid < 416) {
#pragma unroll
            for (int hb = 0; hb < 4; ++hb) {     // 4 h-values per block
                float4 a4[4];
#pragma unroll
                for (int r = 0; r < 4; ++r)
                    a4[r] = *(const float4*)&thL[roffB[r] + (ch << 4) + (hb << 2)];
#pragma unroll
                for (int hh = 0; hh < 4; ++hh) {
                    const int hl = (hb << 2) + hh;        // 0..15 within chunk
                    const float4 b0 = *(const float4*)&pL[(hl << 8) + sw0];
                    const float4 b1 = *(const float4*)&pL[(hl << 8) + sw1];
                    const float* bp0 = (const float*)&b0;
                    const float* bp1 = (const float*)&b1;
#pragma unroll
                    for (int r = 0; r < 4; ++r) {
                        const float a = ((const float*)&a4[r])[hh];
#pragma unroll
                        for (int c = 0; c < 4; ++c) {
                            acc[r][c]     = fmaf(a, bp0[c], acc[r][c]);
                            acc[r][c + 4] = fmaf(a, bp1[c], acc[r][c + 4]);
                        }
                    }
                }
            }
        }
    }

    // ---- LN1 + relu in-register (row k on 32 contiguous lanes) -> flat
    if (tid < 416) {
        float s1[4], s2[4];
#pragma unroll
        for (int r = 0; r < 4; ++r) {
            float a1 = 0.f, a2 = 0.f;
#pragma unroll
            for (int c = 0; c < 8; ++c) { a1 += acc[r][c]; a2 += acc[r][c] * acc[r][c]; }
            s1[r] = a1; s2[r] = a2;
        }
#pragma unroll
        for (int m = 1; m < 32; m <<= 1)
#pragma unroll
            for (int r = 0; r < 4; ++r) {
                s1[r] += __shfl_xor(s1[r], m);
                s2[r] += __shfl_xor(s2[r], m);
            }
        const float4 g0v = *(const float4*)&ln1g[j0B];
        const float4 g1v = *(const float4*)&ln1g[j0B + 4];
        const float4 b0v = *(const float4*)&ln1b[j0B];
        const float4 b1v = *(const float4*)&ln1b[j0B + 4];
        const float* gp = (const float*)&g0v;
        const float* gq = (const float*)&g1v;
        const float* bp = (const float*)&b0v;
        const float* bq = (const float*)&b1v;
#pragma unroll
        for (int r = 0; r < 4; ++r) {
            const int k = (ktB << 2) + r;
            if (k < 49) {
                const float mean = s1[r] * (1.f / 256.f);
                const float var = s2[r] * (1.f / 256.f) - mean * mean;
                const float rstd = rsqrtf(var + LN_EPS);
                float o[8];
#pragma unroll
                for (int c = 0; c < 4; ++c) {
                    o[c]     = fmaxf((acc[r][c]     - mean) * rstd * gp[c] + bp[c], 0.f);
                    o[c + 4] = fmaxf((acc[r][c + 4] - mean) * rstd * gq[c] + bq[c], 0.f);
                }
                ushort4 h4a, h4b, l4a, l4b;
#pragma unroll
                for (int c = 0; c < 4; ++c) {
                    const uint u = __float_as_uint(o[c]);
                    ((ushort*)&h4a)[c] = (ushort)(u >> 16);
                    ((ushort*)&l4a)[c] = (ushort)(__float_as_uint(o[c] - __uint_as_float(u & 0xffff0000u)) >> 16);
                    const uint u2 = __float_as_uint(o[c + 4]);
                    ((ushort*)&h4b)[c] = (ushort)(u2 >> 16);
                    ((ushort*)&l4b)[c] = (ushort)(__float_as_uint(o[c + 4] - __uint_as_float(u2 & 0xffff0000u)) >> 16);
                }
                const size_t fo = (size_t)n * 12544 + k * 256 + j0B;
                *(ushort4*)&fhi[fo] = h4a;
                *(ushort4*)&fhi[fo + 4] = h4b;
                *(ushort4*)&flo[fo] = l4a;
                *(ushort4*)&flo[fo + 4] = l4b;
            }
        }
    }
}

// ---------------------------------------------------------------------------
// K4: reduce 14 split-K partials + Wv_b -> lnv+relu -> +x -> lnf -> out.
// ---------------------------------------------------------------------------
__global__ __launch_bounds__(256) void k4_final(
    const float* __restrict__ wpart, const float* __restrict__ x,
    const float* __restrict__ Wvb,
    const float* __restrict__ lnvg, const float* __restrict__ lnvb,
    const float* __restrict__ lnfg, const float* __restrict__ lnfb,
    float* __restrict__ out)
{
    const int n = (blockIdx.x << 2) + (threadIdx.x >> 6);
    const int lane = threadIdx.x & 63;
    const int j = lane << 2;

    float a0 = 0.f, a1 = 0.f, a2 = 0.f, a3 = 0.f;
#pragma unroll
    for (int s = 0; s < 14; ++s) {
        const float4 p = *(const float4*)&wpart[((size_t)s * 2048 + n) * 256 + j];
        a0 += p.x; a1 += p.y; a2 += p.z; a3 += p.w;
    }
    const float4 bb = *(const float4*)&Wvb[j];
    a0 += bb.x; a1 += bb.y; a2 += bb.z; a3 += bb.w;

    float s1 = a0 + a1 + a2 + a3;
    float s2 = a0*a0 + a1*a1 + a2*a2 + a3*a3;
#pragma unroll
    for (int off = 32; off > 0; off >>= 1) {
        s1 += __shfl_xor(s1, off);
        s2 += __shfl_xor(s2, off);
    }
    float m = s1 * (1.f / 256.f);
    float var = s2 * (1.f / 256.f) - m * m;
    float rr = rsqrtf(var + LN_EPS);
    const float4 g = *(const float4*)&lnvg[j];
    const float4 b = *(const float4*)&lnvb[j];
    const float w0 = fmaxf((a0 - m) * rr * g.x + b.x, 0.f);
    const float w1 = fmaxf((a1 - m) * rr * g.y + b.y, 0.f);
    const float w2 = fmaxf((a2 - m) * rr * g.z + b.z, 0.f);
    const float w3 = fmaxf((a3 - m) * rr * g.w + b.w, 0.f);

    const float4 xv = *(const float4*)&x[(size_t)n * 256 + j];
    const float t0 = xv.x + w0, t1 = xv.y + w1, t2 = xv.z + w2, t3 = xv.w + w3;
    s1 = t0 + t1 + t2 + t3;
    s2 = t0*t0 + t1*t1 + t2*t2 + t3*t3;
#pragma unroll
    for (int off = 32; off > 0; off >>= 1) {
        s1 += __shfl_xor(s1, off);
        s2 += __shfl_xor(s2, off);
    }
    m = s1 * (1.f / 256.f);
    var = s2 * (1.f / 256.f) - m * m;
    rr = rsqrtf(var + LN_EPS);
    const float4 gf = *(const float4*)&lnfg[j];
    const float4 bf = *(const float4*)&lnfb[j];
    float4 o;
    o.x = (t0 - m) * rr * gf.x + bf.x;
    o.y = (t1 - m) * rr * gf.y + bf.y;
    o.z = (t2 - m) * rr * gf.z + bf.z;
    o.w = (t3 - m) * rr * gf.w + bf.w;
    *(float4*)&out[(size_t)n * 256 + j] = o;
}

// ---------------------------------------------------------------------------
extern "C" void kernel_launch(void* const* d_in, const int* in_sizes, int n_in,
                              void* d_out, int out_size, void* d_ws, size_t ws_size,
                              hipStream_t stream)
{
    const float* x    = (const float*)d_in[0];
    const float* v    = (const float*)d_in[1];
    const float* Wq_w = (const float*)d_in[2];
    const float* Wq_b = (const float*)d_in[3];
    const float* ln0g = (const float*)d_in[4];
    const float* ln0b = (const float*)d_in[5];
    const float* ln1g = (const float*)d_in[6];
    const float* ln1b = (const float*)d_in[7];
    const float* Wv_w = (const float*)d_in[8];
    const float* Wv_b = (const float*)d_in[9];
    const float* lnvg = (const float*)d_in[10];
    const float* lnvb = (const float*)d_in[11];
    const float* lnfg = (const float*)d_in[12];
    const float* lnfb = (const float*)d_in[13];
    float* out = (float*)d_out;

    if (ws_size < 371195904ull) return;  // loud failure: out stays poisoned
    char* ws = (char*)d_ws;
    float* q        = (float*)ws;                          // [2048][32768] fp32
    ushort* flat_hi = (ushort*)(ws + 268435456u);          // [2048][12544] bf16
    ushort* flat_lo = (ushort*)(ws + 319815680u);
    ushort* xs_hi   = (ushort*)(ws + 268435456u);          // overlay (dead by K2)
    ushort* xs_lo   = xs_hi + 524288;
    float* wpart    = q;                                   // [14][2048][256] fp32

    k0_split<<<512, 256, 0, stream>>>(x, xs_hi, xs_lo, 131072);

    gemm_sb3<true><<<dim3(16, 256, 1), 256, 0, stream>>>(
        xs_hi, xs_lo, Wq_w, Wq_b, q, 256, 256, 32768, 0, 256);

    k2_dynconv<<<2048, 512, 0, stream>>>(v, q, ln0g, ln0b, ln1g, ln1b,
                                         flat_hi, flat_lo);

    gemm_sb3<false><<<dim3(16, 2, 14), 256, 0, stream>>>(
        flat_hi, flat_lo, Wv_w, nullptr, wpart, 12544, 12544, 256,
        (size_t)2048 * 256, 896);

    k4_final<<<512, 256, 0, stream>>>(wpart, x, Wv_b, lnvg, lnvb, lnfg, lnfb, out);
}

// Round 11
// 735.613 us; speedup vs baseline: 1.2142x; 1.0922x over previous
//
#include <hip/hip_runtime.h>

#define LN_EPS 1e-5f

// Problem constants: N=2048, DIM_IN=256, DIM_V=256, VH=VW=7 (NK=49), H=64
//
// Pipeline:
//   k0_split : x -> xs_hi/xs_lo bf16 planes (trunc split)
//   gemm_sb3 : q[2048][32768] = x @ Wq^T + b   (split-bf16 3-term MFMA)
//   k2       : per-sample dynamic conv (fp32, 512 thr, chunked LDS)
//   gemm_sb3 : wpart[14][2048][256] = flat @ Wv^T partials (split-K=14)
//   k4       : reduce 14 partials + bias -> lnv+relu -> +x -> lnf -> out
//
// Round-11 GEMM changes (K1 counters: 292us, FETCH 207MB≈6x Wq, WRITE 772MB≈2.9x q):
//   - XCD-chunked 1D swizzle: nid=(id&7)*(nwg/8)+id>>3, m fastest -> each XCD
//     owns a contiguous j-range; its B-slice (4.2MB) fits its private 4MB L2.
//   - C-epilogue via per-wave LDS transpose -> float4 global stores (256B
//     segments). Tests/fixes the 2.9x write amplification.
//
// ws layout (byte offsets), total 371,195,904:
//   [0, 268435456)          q fp32 [2048][32768]; reused as wpart after K2
//   [268435456, 371195904)  flat planes: hi ushort[2048][12544], lo @ +51380224
//   xs planes (2 MB) overlay the flat region during K0/K1 (dead by K2).

typedef __attribute__((ext_vector_type(8))) short short8;
typedef __attribute__((ext_vector_type(16))) float f32x16;

// ---------------------------------------------------------------------------
// K0: fp32 -> bf16 hi/lo planes (truncation split: exact a = hi + lo + O(2^-16))
// ---------------------------------------------------------------------------
__global__ __launch_bounds__(256) void k0_split(
    const float* __restrict__ in, ushort* __restrict__ hi,
    ushort* __restrict__ lo, int n4)
{
    const int i = blockIdx.x * 256 + threadIdx.x;
    if (i >= n4) return;
    const float4 f = ((const float4*)in)[i];
    const uint ux = __float_as_uint(f.x), uy = __float_as_uint(f.y);
    const uint uz = __float_as_uint(f.z), uw = __float_as_uint(f.w);
    ushort4 h, l;
    h.x = (ushort)(ux >> 16); h.y = (ushort)(uy >> 16);
    h.z = (ushort)(uz >> 16); h.w = (ushort)(uw >> 16);
    l.x = (ushort)(__float_as_uint(f.x - __uint_as_float(ux & 0xffff0000u)) >> 16);
    l.y = (ushort)(__float_as_uint(f.y - __uint_as_float(uy & 0xffff0000u)) >> 16);
    l.z = (ushort)(__float_as_uint(f.z - __uint_as_float(uz & 0xffff0000u)) >> 16);
    l.w = (ushort)(__float_as_uint(f.w - __uint_as_float(uw & 0xffff0000u)) >> 16);
    ((ushort4*)hi)[i] = h;
    ((ushort4*)lo)[i] = l;
}

// ---------------------------------------------------------------------------
// Split-bf16 3-term MFMA GEMM. 1D grid (nwg = 16*nJT*S), XCD-chunked swizzle.
// Tile 128x128, BK=64, 4 waves 2x2, wave = 2x2 frags of 32x32x16.
// Epilogue: per-wave LDS transpose (16KB quarter) -> float4 stores.
// ---------------------------------------------------------------------------
template<bool HAS_BIAS>
__global__ __launch_bounds__(256, 2) void gemm_sb3(
    const ushort* __restrict__ Ah, const ushort* __restrict__ Al,
    const float* __restrict__ B, const float* __restrict__ bias,
    float* __restrict__ C, int lda, int ldb, int ldc,
    size_t cSplitStride, int kPerSplit, int nJT)
{
    __shared__ __align__(16) ushort smem[32768];     // 64 KB
    ushort* const sAh = smem;
    ushort* const sAl = smem + 8192;
    ushort* const sBh = smem + 16384;
    ushort* const sBl = smem + 24576;

    const int tid = threadIdx.x;
    // XCD-chunked swizzle: each XCD gets a contiguous run of (m-fast) ids.
    const int nwg8 = (int)gridDim.x >> 3;
    const int id = (int)blockIdx.x;
    const int nid = (id & 7) * nwg8 + (id >> 3);
    const int mT = nid & 15;                         // 16 m-tiles (2048/128)
    const int jT = (nid >> 4) % nJT;
    const int sT = (nid >> 4) / nJT;
    const int m0 = mT << 7;
    const int j0 = jT << 7;
    const int ks0 = sT * kPerSplit;
    float* Cb = C + (size_t)sT * cSplitStride;

    const int lane = tid & 63;
    const int wid = tid >> 6;
    const int wr = wid >> 1;
    const int wc = wid & 1;
    const int swz = (lane & 7) << 3;
    const int rA = (wr << 6) + (lane & 31);
    const int rB = (wc << 6) + (lane & 31);
    const int khalf = (lane >> 5) << 3;

    f32x16 acc[2][2];
#pragma unroll
    for (int r = 0; r < 2; ++r)
#pragma unroll
        for (int c = 0; c < 2; ++c)
#pragma unroll
            for (int e = 0; e < 16; ++e) acc[r][c][e] = 0.f;

    for (int kg0 = 0; kg0 < kPerSplit; kg0 += 64) {
        const int kg = ks0 + kg0;

        uint4 av[8];
#pragma unroll
        for (int p = 0; p < 2; ++p) {
            const ushort* src = p ? Al : Ah;
#pragma unroll
            for (int i = 0; i < 4; ++i) {
                const int idx = tid + (i << 8);
                const int row = idx >> 3;
                const int c8 = (idx & 7) << 3;
                av[p * 4 + i] = *(const uint4*)(src + (size_t)(m0 + row) * lda + kg + c8);
            }
        }
        float4 bv[8];
#pragma unroll
        for (int i = 0; i < 8; ++i) {
            const int idx = tid + (i << 8);
            const int row = idx >> 4;
            const int c4 = (idx & 15) << 2;
            bv[i] = *(const float4*)(B + (size_t)(j0 + row) * ldb + kg + c4);
        }

        if (kg0 > 0) __syncthreads();

#pragma unroll
        for (int p = 0; p < 2; ++p) {
            ushort* dst = p ? sAl : sAh;
#pragma unroll
            for (int i = 0; i < 4; ++i) {
                const int idx = tid + (i << 8);
                const int row = idx >> 3;
                const int c8 = (idx & 7) << 3;
                *(uint4*)&dst[((row << 6) + c8) ^ ((row & 7) << 3)] = av[p * 4 + i];
            }
        }
#pragma unroll
        for (int i = 0; i < 8; ++i) {
            const int idx = tid + (i << 8);
            const int row = idx >> 4;
            const int c4 = (idx & 15) << 2;
            const uint ux = __float_as_uint(bv[i].x), uy = __float_as_uint(bv[i].y);
            const uint uz = __float_as_uint(bv[i].z), uw = __float_as_uint(bv[i].w);
            const float lx = bv[i].x - __uint_as_float(ux & 0xffff0000u);
            const float ly = bv[i].y - __uint_as_float(uy & 0xffff0000u);
            const float lz = bv[i].z - __uint_as_float(uz & 0xffff0000u);
            const float lw = bv[i].w - __uint_as_float(uw & 0xffff0000u);
            const uint h01 = (ux >> 16) | (uy & 0xffff0000u);
            const uint h23 = (uz >> 16) | (uw & 0xffff0000u);
            const uint l01 = (__float_as_uint(lx) >> 16) | (__float_as_uint(ly) & 0xffff0000u);
            const uint l23 = (__float_as_uint(lz) >> 16) | (__float_as_uint(lw) & 0xffff0000u);
            const int sidx = ((row << 6) + c4) ^ ((row & 7) << 3);
            *(uint2*)&sBh[sidx] = make_uint2(h01, h23);
            *(uint2*)&sBl[sidx] = make_uint2(l01, l23);
        }
        __syncthreads();

#pragma unroll
        for (int ks = 0; ks < 4; ++ks) {
            const int kf = (ks << 4) + khalf;
            const int ia0 = ((rA << 6) + kf) ^ swz;
            const int ia1 = (((rA + 32) << 6) + kf) ^ swz;
            const int ib0 = ((rB << 6) + kf) ^ swz;
            const int ib1 = (((rB + 32) << 6) + kf) ^ swz;
            const short8 a0h = *(const short8*)&sAh[ia0];
            const short8 a0l = *(const short8*)&sAl[ia0];
            const short8 a1h = *(const short8*)&sAh[ia1];
            const short8 a1l = *(const short8*)&sAl[ia1];
            const short8 b0h = *(const short8*)&sBh[ib0];
            const short8 b0l = *(const short8*)&sBl[ib0];
            const short8 b1h = *(const short8*)&sBh[ib1];
            const short8 b1l = *(const short8*)&sBl[ib1];

            acc[0][0] = __builtin_amdgcn_mfma_f32_32x32x16_bf16(a0h, b0h, acc[0][0], 0, 0, 0);
            acc[0][1] = __builtin_amdgcn_mfma_f32_32x32x16_bf16(a0h, b1h, acc[0][1], 0, 0, 0);
            acc[1][0] = __builtin_amdgcn_mfma_f32_32x32x16_bf16(a1h, b0h, acc[1][0], 0, 0, 0);
            acc[1][1] = __builtin_amdgcn_mfma_f32_32x32x16_bf16(a1h, b1h, acc[1][1], 0, 0, 0);
            acc[0][0] = __builtin_amdgcn_mfma_f32_32x32x16_bf16(a0h, b0l, acc[0][0], 0, 0, 0);
            acc[0][1] = __builtin_amdgcn_mfma_f32_32x32x16_bf16(a0h, b1l, acc[0][1], 0, 0, 0);
            acc[1][0] = __builtin_amdgcn_mfma_f32_32x32x16_bf16(a1h, b0l, acc[1][0], 0, 0, 0);
            acc[1][1] = __builtin_amdgcn_mfma_f32_32x32x16_bf16(a1h, b1l, acc[1][1], 0, 0, 0);
            acc[0][0] = __builtin_amdgcn_mfma_f32_32x32x16_bf16(a0l, b0h, acc[0][0], 0, 0, 0);
            acc[0][1] = __builtin_amdgcn_mfma_f32_32x32x16_bf16(a0l, b1h, acc[0][1], 0, 0, 0);
            acc[1][0] = __builtin_amdgcn_mfma_f32_32x32x16_bf16(a1l, b0h, acc[1][0], 0, 0, 0);
            acc[1][1] = __builtin_amdgcn_mfma_f32_32x32x16_bf16(a1l, b1h, acc[1][1], 0, 0, 0);
        }
    }

    // ---- epilogue: per-wave LDS transpose -> float4 stores
    __syncthreads();                                  // all waves done with tiles
    float* cbuf = (float*)smem + (wid << 12);         // 16 KB quarter per wave
#pragma unroll
    for (int rb = 0; rb < 2; ++rb)
#pragma unroll
        for (int cb = 0; cb < 2; ++cb) {
            const int c = (cb << 5) + (lane & 31);
            const int r0 = (rb << 5) + ((lane >> 5) << 2);
#pragma unroll
            for (int reg = 0; reg < 16; ++reg) {
                const int rr = (reg & 3) + ((reg >> 2) << 3);
                cbuf[((r0 + rr) << 6) + c] = acc[rb][cb][reg];
            }
        }
    // same-wave ds ordering: no barrier needed before read-back
    const int colq = (lane & 15) << 2;
    const int rsub = lane >> 4;                       // 0..3
    const int gc = j0 + (wc << 6) + colq;
    float4 bb = make_float4(0.f, 0.f, 0.f, 0.f);
    if (HAS_BIAS) bb = *(const float4*)&bias[gc];
#pragma unroll
    for (int it = 0; it < 16; ++it) {
        const int rl = (it << 2) + rsub;              // 0..63
        float4 val = *(const float4*)&cbuf[(rl << 6) + colq];
        val.x += bb.x; val.y += bb.y; val.z += bb.z; val.w += bb.w;
        *(float4*)(Cb + (size_t)(m0 + (wr << 6) + rl) * ldc + gc) = val;
    }
}

// ---------------------------------------------------------------------------
// K2 (v4, verified round 10): per-sample dynamic conv, 512 threads, 43 KB LDS.
// ---------------------------------------------------------------------------
__global__ __launch_bounds__(512, 4) void k2_dynconv(
    const float* __restrict__ v, const float* __restrict__ q,
    const float* __restrict__ ln0g, const float* __restrict__ ln0b,
    const float* __restrict__ ln1g, const float* __restrict__ ln1b,
    ushort* __restrict__ fhi, ushort* __restrict__ flo)
{
    __shared__ __align__(16) float sm[10756];    // 43,024 B
    float* const thL = sm;                       // [49][68] = 3332
    float* const vL  = sm + 3332;                // [64][52] = 3328
    float* const pL  = sm + 6660;                // 4096

    const int n = blockIdx.x;
    const int tid = threadIdx.x;
    const float* vrow = v + (size_t)n * 12544;
    const float* qrow = q + (size_t)n * 32768;

    const int ktA = tid >> 4;
    const int h0A = (tid & 15) << 2;
    float ta[4][4];
#pragma unroll
    for (int r = 0; r < 4; ++r)
#pragma unroll
        for (int c = 0; c < 4; ++c) ta[r][c] = 0.f;

    for (int ch = 0; ch < 4; ++ch) {
        if (ch) __syncthreads();
        for (int i4 = tid; i4 < 784; i4 += 512) {
            const float4 f = *(const float4*)(vrow + ch * 3136 + (i4 << 2));
            const int base = i4 << 2;
#pragma unroll
            for (int e = 0; e < 4; ++e) {
                const int idx = base + e;
                const int dv = (int)(((uint)idx * 85599u) >> 22);
                const int k = idx - dv * 49;
                vL[dv * 52 + k] = ((const float*)&f)[e];
            }
        }
        for (int i = tid; i < 1024; i += 512)
            *(float4*)&pL[i << 2] = *(const float4*)(qrow + (ch << 12) + (i << 2));
        __syncthreads();

        if (tid < 208) {
#pragma unroll 2
            for (int dv = 0; dv < 64; ++dv) {
                const float4 a4 = *(const float4*)&vL[dv * 52 + (ktA << 2)];
                const float4 b4 = *(const float4*)&pL[(dv << 6) + h0A];
                const float* ap = (const float*)&a4;
                const float* bp = (const float*)&b4;
#pragma unroll
                for (int r = 0; r < 4; ++r)
#pragma unroll
                    for (int c = 0; c < 4; ++c)
                        ta[r][c] = fmaf(ap[r], bp[c], ta[r][c]);
            }
        }
    }

    if (tid < 208) {
        float s1[4], s2[4];
#pragma unroll
        for (int r = 0; r < 4; ++r) {
            s1[r] = ta[r][0] + ta[r][1] + ta[r][2] + ta[r][3];
            s2[r] = ta[r][0]*ta[r][0] + ta[r][1]*ta[r][1]
                  + ta[r][2]*ta[r][2] + ta[r][3]*ta[r][3];
        }
#pragma unroll
        for (int m = 1; m < 16; m <<= 1)
#pragma unroll
            for (int r = 0; r < 4; ++r) {
                s1[r] += __shfl_xor(s1[r], m);
                s2[r] += __shfl_xor(s2[r], m);
            }
        const float4 g4 = *(const float4*)&ln0g[h0A];
        const float4 b4 = *(const float4*)&ln0b[h0A];
        const float* gp = (const float*)&g4;
        const float* bp = (const float*)&b4;
#pragma unroll
        for (int r = 0; r < 4; ++r) {
            const int k = (ktA << 2) + r;
            if (k < 49) {
                const float mean = s1[r] * (1.f / 64.f);
                const float var = s2[r] * (1.f / 64.f) - mean * mean;
                const float rstd = rsqrtf(var + LN_EPS);
                float4 o;
                o.x = fmaxf((ta[r][0] - mean) * rstd * gp[0] + bp[0], 0.f);
                o.y = fmaxf((ta[r][1] - mean) * rstd * gp[1] + bp[1], 0.f);
                o.z = fmaxf((ta[r][2] - mean) * rstd * gp[2] + bp[2], 0.f);
                o.w = fmaxf((ta[r][3] - mean) * rstd * gp[3] + bp[3], 0.f);
                *(float4*)&thL[k * 68 + h0A] = o;
            }
        }
    }
    __syncthreads();

    const int ktB = tid >> 5;
    const int j0B = (tid & 31) << 3;
    const int g0 = (tid & 31) << 1;
    const int sw0 = (g0 ^ (g0 >> 3)) << 2;
    const int sw1 = ((g0 + 1) ^ ((g0 + 1) >> 3)) << 2;
    int roffB[4];
#pragma unroll
    for (int r = 0; r < 4; ++r) {
        const int k = (ktB << 2) + r;
        roffB[r] = (k < 49 ? k : 48) * 68;
    }
    float acc[4][8];
#pragma unroll
    for (int r = 0; r < 4; ++r)
#pragma unroll
        for (int c = 0; c < 8; ++c) acc[r][c] = 0.f;

    for (int ch = 0; ch < 4; ++ch) {
        if (ch) __syncthreads();
        for (int i = tid; i < 1024; i += 512) {
            const int h = i >> 6;
            const int g = i & 63;
            const int s = g ^ (g >> 3);
            *(float4*)&pL[(h << 8) + (s << 2)] =
                *(const float4*)(qrow + 16384 + (ch << 12) + (i << 2));
        }
        __syncthreads();

        if (tid < 416) {
#pragma unroll
            for (int hb = 0; hb < 4; ++hb) {
                float4 a4[4];
#pragma unroll
                for (int r = 0; r < 4; ++r)
                    a4[r] = *(const float4*)&thL[roffB[r] + (ch << 4) + (hb << 2)];
#pragma unroll
                for (int hh = 0; hh < 4; ++hh) {
                    const int hl = (hb << 2) + hh;
                    const float4 b0 = *(const float4*)&pL[(hl << 8) + sw0];
                    const float4 b1 = *(const float4*)&pL[(hl << 8) + sw1];
                    const float* bp0 = (const float*)&b0;
                    const float* bp1 = (const float*)&b1;
#pragma unroll
                    for (int r = 0; r < 4; ++r) {
                        const float a = ((const float*)&a4[r])[hh];
#pragma unroll
                        for (int c = 0; c < 4; ++c) {
                            acc[r][c]     = fmaf(a, bp0[c], acc[r][c]);
                            acc[r][c + 4] = fmaf(a, bp1[c], acc[r][c + 4]);
                        }
                    }
                }
            }
        }
    }

    if (tid < 416) {
        float s1[4], s2[4];
#pragma unroll
        for (int r = 0; r < 4; ++r) {
            float a1 = 0.f, a2 = 0.f;
#pragma unroll
            for (int c = 0; c < 8; ++c) { a1 += acc[r][c]; a2 += acc[r][c] * acc[r][c]; }
            s1[r] = a1; s2[r] = a2;
        }
#pragma unroll
        for (int m = 1; m < 32; m <<= 1)
#pragma unroll
            for (int r = 0; r < 4; ++r) {
                s1[r] += __shfl_xor(s1[r], m);
                s2[r] += __shfl_xor(s2[r], m);
            }
        const float4 g0v = *(const float4*)&ln1g[j0B];
        const float4 g1v = *(const float4*)&ln1g[j0B + 4];
        const float4 b0v = *(const float4*)&ln1b[j0B];
        const float4 b1v = *(const float4*)&ln1b[j0B + 4];
        const float* gp = (const float*)&g0v;
        const float* gq = (const float*)&g1v;
        const float* bp = (const float*)&b0v;
        const float* bq = (const float*)&b1v;
#pragma unroll
        for (int r = 0; r < 4; ++r) {
            const int k = (ktB << 2) + r;
            if (k < 49) {
                const float mean = s1[r] * (1.f / 256.f);
                const float var = s2[r] * (1.f / 256.f) - mean * mean;
                const float rstd = rsqrtf(var + LN_EPS);
                float o[8];
#pragma unroll
                for (int c = 0; c < 4; ++c) {
                    o[c]     = fmaxf((acc[r][c]     - mean) * rstd * gp[c] + bp[c], 0.f);
                    o[c + 4] = fmaxf((acc[r][c + 4] - mean) * rstd * gq[c] + bq[c], 0.f);
                }
                ushort4 h4a, h4b, l4a, l4b;
#pragma unroll
                for (int c = 0; c < 4; ++c) {
                    const uint u = __float_as_uint(o[c]);
                    ((ushort*)&h4a)[c] = (ushort)(u >> 16);
                    ((ushort*)&l4a)[c] = (ushort)(__float_as_uint(o[c] - __uint_as_float(u & 0xffff0000u)) >> 16);
                    const uint u2 = __float_as_uint(o[c + 4]);
                    ((ushort*)&h4b)[c] = (ushort)(u2 >> 16);
                    ((ushort*)&l4b)[c] = (ushort)(__float_as_uint(o[c + 4] - __uint_as_float(u2 & 0xffff0000u)) >> 16);
                }
                const size_t fo = (size_t)n * 12544 + k * 256 + j0B;
                *(ushort4*)&fhi[fo] = h4a;
                *(ushort4*)&fhi[fo + 4] = h4b;
                *(ushort4*)&flo[fo] = l4a;
                *(ushort4*)&flo[fo + 4] = l4b;
            }
        }
    }
}

// ---------------------------------------------------------------------------
// K4: reduce 14 split-K partials + Wv_b -> lnv+relu -> +x -> lnf -> out.
// ---------------------------------------------------------------------------
__global__ __launch_bounds__(256) void k4_final(
    const float* __restrict__ wpart, const float* __restrict__ x,
    const float* __restrict__ Wvb,
    const float* __restrict__ lnvg, const float* __restrict__ lnvb,
    const float* __restrict__ lnfg, const float* __restrict__ lnfb,
    float* __restrict__ out)
{
    const int n = (blockIdx.x << 2) + (threadIdx.x >> 6);
    const int lane = threadIdx.x & 63;
    const int j = lane << 2;

    float a0 = 0.f, a1 = 0.f, a2 = 0.f, a3 = 0.f;
#pragma unroll
    for (int s = 0; s < 14; ++s) {
        const float4 p = *(const float4*)&wpart[((size_t)s * 2048 + n) * 256 + j];
        a0 += p.x; a1 += p.y; a2 += p.z; a3 += p.w;
    }
    const float4 bb = *(const float4*)&Wvb[j];
    a0 += bb.x; a1 += bb.y; a2 += bb.z; a3 += bb.w;

    float s1 = a0 + a1 + a2 + a3;
    float s2 = a0*a0 + a1*a1 + a2*a2 + a3*a3;
#pragma unroll
    for (int off = 32; off > 0; off >>= 1) {
        s1 += __shfl_xor(s1, off);
        s2 += __shfl_xor(s2, off);
    }
    float m = s1 * (1.f / 256.f);
    float var = s2 * (1.f / 256.f) - m * m;
    float rr = rsqrtf(var + LN_EPS);
    const float4 g = *(const float4*)&lnvg[j];
    const float4 b = *(const float4*)&lnvb[j];
    const float w0 = fmaxf((a0 - m) * rr * g.x + b.x, 0.f);
    const float w1 = fmaxf((a1 - m) * rr * g.y + b.y, 0.f);
    const float w2 = fmaxf((a2 - m) * rr * g.z + b.z, 0.f);
    const float w3 = fmaxf((a3 - m) * rr * g.w + b.w, 0.f);

    const float4 xv = *(const float4*)&x[(size_t)n * 256 + j];
    const float t0 = xv.x + w0, t1 = xv.y + w1, t2 = xv.z + w2, t3 = xv.w + w3;
    s1 = t0 + t1 + t2 + t3;
    s2 = t0*t0 + t1*t1 + t2*t2 + t3*t3;
#pragma unroll
    for (int off = 32; off > 0; off >>= 1) {
        s1 += __shfl_xor(s1, off);
        s2 += __shfl_xor(s2, off);
    }
    m = s1 * (1.f / 256.f);
    var = s2 * (1.f / 256.f) - m * m;
    rr = rsqrtf(var + LN_EPS);
    const float4 gf = *(const float4*)&lnfg[j];
    const float4 bf = *(const float4*)&lnfb[j];
    float4 o;
    o.x = (t0 - m) * rr * gf.x + bf.x;
    o.y = (t1 - m) * rr * gf.y + bf.y;
    o.z = (t2 - m) * rr * gf.z + bf.z;
    o.w = (t3 - m) * rr * gf.w + bf.w;
    *(float4*)&out[(size_t)n * 256 + j] = o;
}

// ---------------------------------------------------------------------------
extern "C" void kernel_launch(void* const* d_in, const int* in_sizes, int n_in,
                              void* d_out, int out_size, void* d_ws, size_t ws_size,
                              hipStream_t stream)
{
    const float* x    = (const float*)d_in[0];
    const float* v    = (const float*)d_in[1];
    const float* Wq_w = (const float*)d_in[2];
    const float* Wq_b = (const float*)d_in[3];
    const float* ln0g = (const float*)d_in[4];
    const float* ln0b = (const float*)d_in[5];
    const float* ln1g = (const float*)d_in[6];
    const float* ln1b = (const float*)d_in[7];
    const float* Wv_w = (const float*)d_in[8];
    const float* Wv_b = (const float*)d_in[9];
    const float* lnvg = (const float*)d_in[10];
    const float* lnvb = (const float*)d_in[11];
    const float* lnfg = (const float*)d_in[12];
    const float* lnfb = (const float*)d_in[13];
    float* out = (float*)d_out;

    if (ws_size < 371195904ull) return;  // loud failure: out stays poisoned
    char* ws = (char*)d_ws;
    float* q        = (float*)ws;                          // [2048][32768] fp32
    ushort* flat_hi = (ushort*)(ws + 268435456u);          // [2048][12544] bf16
    ushort* flat_lo = (ushort*)(ws + 319815680u);
    ushort* xs_hi   = (ushort*)(ws + 268435456u);          // overlay (dead by K2)
    ushort* xs_lo   = xs_hi + 524288;
    float* wpart    = q;                                   // [14][2048][256] fp32

    k0_split<<<512, 256, 0, stream>>>(x, xs_hi, xs_lo, 131072);

    // K1: 1D grid 4096 = 16 m x 256 j (nJT=256, S=1)
    gemm_sb3<true><<<4096, 256, 0, stream>>>(
        xs_hi, xs_lo, Wq_w, Wq_b, q, 256, 256, 32768, 0, 256, 256);

    k2_dynconv<<<2048, 512, 0, stream>>>(v, q, ln0g, ln0b, ln1g, ln1b,
                                         flat_hi, flat_lo);

    // K3: 1D grid 448 = 16 m x 2 j x 14 s (nJT=2)
    gemm_sb3<false><<<448, 256, 0, stream>>>(
        flat_hi, flat_lo, Wv_w, nullptr, wpart, 12544, 12544, 256,
        (size_t)2048 * 256, 896, 2);

    k4_final<<<512, 256, 0, stream>>>(wpart, x, Wv_b, lnvg, lnvb, lnfg, lnfb, out);
}